// Round 14
// baseline (93.870 us; speedup 1.0000x reference)
//
#include <hip/hip_runtime.h>
#include <hip/hip_bf16.h>

#define T_SEQ 2048
#define E_DIM 2048
#define D_HEAD 64
#define B_SZ 4
#define NROWS (B_SZ * T_SEQ)  // 8192

typedef __attribute__((ext_vector_type(8))) short bf16x8;
typedef __attribute__((ext_vector_type(4))) float f32x4;
typedef __attribute__((ext_vector_type(4))) unsigned short u16x4;
typedef __attribute__((ext_vector_type(8))) unsigned short u16x8;

__device__ __forceinline__ unsigned short f2bf(float x) {
    __hip_bfloat16 h = __float2bfloat16(x);
    return *reinterpret_cast<unsigned short*>(&h);
}

__device__ __forceinline__ u16x8 cvt8(float4 a, float4 b) {
    u16x8 t;
    t[0] = f2bf(a.x); t[1] = f2bf(a.y); t[2] = f2bf(a.z); t[3] = f2bf(a.w);
    t[4] = f2bf(b.x); t[5] = f2bf(b.y); t[6] = f2bf(b.z); t[7] = f2bf(b.w);
    return t;
}

// pack two f32x4 (lo k, hi k) into an MFMA A/B fragment
__device__ __forceinline__ bf16x8 cvtfrag2(f32x4 lo, f32x4 hi) {
    bf16x8 f;
    #pragma unroll
    for (int j = 0; j < 4; ++j) {
        f[j]     = (short)f2bf(lo[j]);
        f[4 + j] = (short)f2bf(hi[j]);
    }
    return f;
}

// MFMA A/B fragment from a [row][k] bf16 buffer: k = base..base+3, base+16..+19
__device__ __forceinline__ bf16x8 ldfrag(const unsigned short* p) {
    u16x4 lo = *(const u16x4*)p;
    u16x4 hi = *(const u16x4*)(p + 16);
    bf16x8 f;
    #pragma unroll
    for (int j = 0; j < 4; ++j) { f[j] = (short)lo[j]; f[4 + j] = (short)hi[j]; }
    return f;
}

// lgkmcnt(0) drain for LDS writes before a raw barrier
__device__ __forceinline__ void lds_fence_barrier() {
    asm volatile("s_waitcnt lgkmcnt(0)" ::: "memory");
    __builtin_amdgcn_s_barrier();
}

// ---------------------------------------------------------------------------
// W -> bf16 packed in MFMA B-fragment order:
// Wp byte (f*64 + k32)*1024 + l*16 holds lane l's bf16x8 for frag (f, k32);
// f = col/16 in 0..11, k32 = k/32 in 0..63.
// ---------------------------------------------------------------------------
__global__ __launch_bounds__(256) void wcvt_kernel(
    const float* __restrict__ Wq, const float* __restrict__ Wk,
    const float* __restrict__ Wv, unsigned short* __restrict__ Wp)
{
    const int gid = blockIdx.x * 256 + threadIdx.x;   // 0..49151
    const int l    = gid & 63;
    const int k32  = (gid >> 6) & 63;
    const int f    = gid >> 12;                       // 0..11
    const int r    = l & 15;
    const int g    = l >> 4;
    const int n    = 16 * f + r;                      // 0..191
    const int pj   = n >> 6;
    const int o    = n & 63;
    const float* __restrict__ src = (pj == 0) ? Wq : (pj == 1) ? Wk : Wv;
    const float* p = src + (size_t)o * E_DIM + k32 * 32 + g * 4;
    float4 a = *(const float4*)p;
    float4 b = *(const float4*)(p + 16);
    *(u16x8*)(Wp + (size_t)gid * 8) = cvt8(a, b);
}

// ---------------------------------------------------------------------------
// QKV projection partials, MAX-TLP copy-kernel style. NO LDS, NO barriers,
// NO inter-wave cooperation. Split-K=2: block (rt, ks) computes a 16-row x
// 192-col x 1024-K fp32 partial. 1024 blocks x 256 thr = 4 independent waves
// (wave = wn slice of 48 cols), 16 waves/CU: latency hidden by TLP exactly
// like the 6.9 TB/s copy kernel. A-frags per-lane from global x (L1-shared
// across the 4 wn waves); B-frags coalesced 16B/lane from packed Wp (L2).
// ---------------------------------------------------------------------------
__global__ __launch_bounds__(256, 4) void proj_part_kernel(
    const float* __restrict__ x, const unsigned short* __restrict__ Wp,
    float* __restrict__ Cpart)
{
    const int tid = threadIdx.x;
    const int wn  = tid >> 6;   // 0..3 : 48-col slice
    const int l   = tid & 63;
    const int r   = l & 15;
    const int g   = l >> 4;
    const int ks  = blockIdx.x & 1;        // K half
    const int rt  = blockIdx.x >> 1;       // row tile 0..511
    const int row0 = rt * 16;

    const float* xrow = x + (size_t)(row0 + r) * E_DIM + ks * 1024 + 4 * g;
    const unsigned char* wpb = (const unsigned char*)Wp + l * 16;

    f32x4 acc[3];
    #pragma unroll
    for (int ff = 0; ff < 3; ++ff) acc[ff] = (f32x4){0.f, 0.f, 0.f, 0.f};

    #pragma unroll 4
    for (int t = 0; t < 16; ++t) {
        bf16x8 af[2];
        #pragma unroll
        for (int kk = 0; kk < 2; ++kk) {
            f32x4 lo = *(const f32x4*)(xrow + t * 64 + kk * 32);
            f32x4 hi = *(const f32x4*)(xrow + t * 64 + kk * 32 + 16);
            af[kk] = cvtfrag2(lo, hi);
        }
        #pragma unroll
        for (int ff = 0; ff < 3; ++ff) {
            const int f = wn * 3 + ff;
            #pragma unroll
            for (int kk = 0; kk < 2; ++kk) {
                bf16x8 bfm = *(const bf16x8*)(
                    wpb + (size_t)(f * 64 + ks * 32 + 2 * t + kk) * 1024);
                acc[ff] = __builtin_amdgcn_mfma_f32_16x16x32_bf16(
                    af[kk], bfm, acc[ff], 0, 0, 0);
            }
        }
    }

    // write fp32 partial: Cpart[ks][row][n], n = 16f + r
    float* cp = Cpart + (size_t)ks * NROWS * 192;
    #pragma unroll
    for (int ff = 0; ff < 3; ++ff) {
        const int n = 16 * (wn * 3 + ff) + r;
        #pragma unroll
        for (int j = 0; j < 4; ++j)
            cp[(size_t)(row0 + 4 * g + j) * 192 + n] = acc[ff][j];
    }
}

// ---------------------------------------------------------------------------
// Finalize: sum K-partials, add bias, fold softmax scale into q, emit bf16.
// gid covers 8192 rows x 48 groups of 4 cols (coalesced f32x4 reads).
// ---------------------------------------------------------------------------
__global__ __launch_bounds__(256) void proj_fin_kernel(
    const float* __restrict__ Cpart,
    const float* __restrict__ bq, const float* __restrict__ bk,
    const float* __restrict__ bv,
    __hip_bfloat16* __restrict__ qb, __hip_bfloat16* __restrict__ kb,
    __hip_bfloat16* __restrict__ vb)
{
    const int gid = blockIdx.x * 256 + threadIdx.x;   // 0..393215
    const int row = gid / 48;
    const int n0  = (gid % 48) * 4;                   // 4 cols, same projection
    const int pj  = n0 >> 6;
    const int o   = n0 & 63;
    f32x4 a = *(const f32x4*)(Cpart + (size_t)row * 192 + n0);
    f32x4 b = *(const f32x4*)(Cpart + (size_t)NROWS * 192 + (size_t)row * 192 + n0);
    const float* bias = (pj == 0) ? bq : (pj == 1) ? bk : bv;
    __hip_bfloat16* dst = (pj == 0) ? qb : (pj == 1) ? kb : vb;
    const float scale = (pj == 0) ? 0.18033688011112042f : 1.0f;  // 0.125*log2e
    u16x4 outv;
    #pragma unroll
    for (int j = 0; j < 4; ++j)
        outv[j] = f2bf((a[j] + b[j] + bias[o + j]) * scale);
    *(u16x4*)((unsigned short*)dst + (size_t)row * D_HEAD + o) = outv;
}

// ---------------------------------------------------------------------------
// Split-KV flash attention partials (unchanged from round 7/8).
// ---------------------------------------------------------------------------
#define LDK 72
#define LDV 68
#define LDP 68

__global__ __launch_bounds__(128) void attn_part_kernel(
    const __hip_bfloat16* __restrict__ qg, const __hip_bfloat16* __restrict__ kg,
    const __hip_bfloat16* __restrict__ vg, float* __restrict__ Op,
    float* __restrict__ Ml, int tpc, int nch)
{
    const int qt = blockIdx.x;
    const int ch = blockIdx.y;
    const int total64 = qt / 2 + 1;
    if (ch * tpc >= total64) return;

    __shared__ unsigned short Kl[64 * LDK];
    __shared__ unsigned short Vt[64 * LDV];
    __shared__ unsigned short Pl[2 * 16 * LDP];

    const int tid = threadIdx.x;
    const int w   = tid >> 6;
    const int l   = tid & 63;
    const int r   = l & 15;
    const int g   = l >> 4;
    const int q0  = qt * 32;
    const int b   = blockIdx.z;
    const size_t base = (size_t)b * T_SEQ;

    const unsigned short* qb16 = (const unsigned short*)qg;
    const unsigned short* kb16 = (const unsigned short*)kg;
    const unsigned short* vb16 = (const unsigned short*)vg;

    const unsigned short* qrow = qb16 + (base + q0 + 16 * w + r) * D_HEAD;
    bf16x8 qf[2];
    #pragma unroll
    for (int kk = 0; kk < 2; ++kk)
        qf[kk] = ldfrag(qrow + 32 * kk + 4 * g);

    f32x4 acc_o[4];
    #pragma unroll
    for (int dn = 0; dn < 4; ++dn) acc_o[dn] = (f32x4){0.f, 0.f, 0.f, 0.f};
    float m4[4] = {-1e30f, -1e30f, -1e30f, -1e30f};
    float l4[4] = {0.f, 0.f, 0.f, 0.f};

    unsigned short* pw = &Pl[w * 16 * LDP];
    const int ntiles = min(tpc, total64 - ch * tpc);
    const int y = tid & 15, z = tid >> 4;   // V-staging coords
    const int s0base = ch * tpc * 64;

    u16x8 kr[4];
    u16x4 va4[4], vb4[4];

    auto issue = [&](int s0) {
        #pragma unroll
        for (int i = 0; i < 4; ++i) {
            const int c = tid + i * 128;
            kr[i] = *(const u16x8*)(kb16 + (base + s0 + (c >> 3)) * D_HEAD + (c & 7) * 8);
        }
        #pragma unroll
        for (int m = 0; m < 4; ++m) {
            const int sl = 2 * (z + 8 * m);
            const int d0 = y * 4;
            va4[m] = *(const u16x4*)(vb16 + (base + s0 + sl) * D_HEAD + d0);
            vb4[m] = *(const u16x4*)(vb16 + (base + s0 + sl + 1) * D_HEAD + d0);
        }
    };

    issue(s0base);

    for (int it = 0; it < ntiles; ++it) {
        const int s0 = s0base + it * 64;

        __builtin_amdgcn_s_barrier();   // prev tile's LDS reads done

        #pragma unroll
        for (int i = 0; i < 4; ++i) {
            const int c = tid + i * 128;
            *(u16x8*)(&Kl[(c >> 3) * LDK + (c & 7) * 8]) = kr[i];
        }
        #pragma unroll
        for (int m = 0; m < 4; ++m) {
            const int sl = 2 * (z + 8 * m);
            const int d0 = y * 4;
            #pragma unroll
            for (int i = 0; i < 4; ++i) {
                unsigned int pr = (unsigned int)(unsigned short)va4[m][i] |
                                  ((unsigned int)(unsigned short)vb4[m][i] << 16);
                *(unsigned int*)&Vt[(d0 + i) * LDV + sl] = pr;
            }
        }
        lds_fence_barrier();

        if (it + 1 < ntiles) issue(s0 + 64);

        f32x4 s_acc[4];
        #pragma unroll
        for (int nt = 0; nt < 4; ++nt) s_acc[nt] = (f32x4){0.f, 0.f, 0.f, 0.f};
        #pragma unroll
        for (int nt = 0; nt < 4; ++nt)
            #pragma unroll
            for (int kk = 0; kk < 2; ++kk) {
                bf16x8 bf = ldfrag(&Kl[(nt * 16 + r) * LDK + kk * 32 + 4 * g]);
                s_acc[nt] = __builtin_amdgcn_mfma_f32_16x16x32_bf16(qf[kk], bf, s_acc[nt], 0, 0, 0);
            }

        if (s0 + 64 > q0) {
            #pragma unroll
            for (int nt = 0; nt < 4; ++nt)
                #pragma unroll
                for (int j = 0; j < 4; ++j)
                    if (s0 + nt * 16 + r > q0 + 16 * w + 4 * g + j)
                        s_acc[nt][j] = -1e30f;
        }

        float tm[4];
        #pragma unroll
        for (int j = 0; j < 4; ++j)
            tm[j] = fmaxf(fmaxf(s_acc[0][j], s_acc[1][j]),
                          fmaxf(s_acc[2][j], s_acc[3][j]));
        #pragma unroll
        for (int mask = 1; mask < 16; mask <<= 1)
            #pragma unroll
            for (int j = 0; j < 4; ++j)
                tm[j] = fmaxf(tm[j], __shfl_xor(tm[j], mask));

        float p[4][4], rs[4];
        #pragma unroll
        for (int j = 0; j < 4; ++j) {
            const float mn = fmaxf(m4[j], tm[j]);
            const float sc = exp2f(m4[j] - mn);
            m4[j] = mn;
            rs[j] = 0.f;
            #pragma unroll
            for (int nt = 0; nt < 4; ++nt) {
                p[nt][j] = exp2f(s_acc[nt][j] - mn);
                rs[j] += p[nt][j];
            }
            l4[j] *= sc;
            acc_o[0][j] *= sc; acc_o[1][j] *= sc;
            acc_o[2][j] *= sc; acc_o[3][j] *= sc;
        }
        #pragma unroll
        for (int mask = 1; mask < 16; mask <<= 1)
            #pragma unroll
            for (int j = 0; j < 4; ++j)
                rs[j] += __shfl_xor(rs[j], mask);
        #pragma unroll
        for (int j = 0; j < 4; ++j) l4[j] += rs[j];

        #pragma unroll
        for (int nt = 0; nt < 4; ++nt)
            #pragma unroll
            for (int j = 0; j < 4; ++j)
                pw[(4 * g + j) * LDP + nt * 16 + r] = f2bf(p[nt][j]);

        bf16x8 pf[2];
        #pragma unroll
        for (int kk = 0; kk < 2; ++kk)
            pf[kk] = ldfrag(&pw[r * LDP + kk * 32 + 4 * g]);

        #pragma unroll
        for (int dn = 0; dn < 4; ++dn)
            #pragma unroll
            for (int kk = 0; kk < 2; ++kk) {
                bf16x8 vf = ldfrag(&Vt[(dn * 16 + r) * LDV + kk * 32 + 4 * g]);
                acc_o[dn] = __builtin_amdgcn_mfma_f32_16x16x32_bf16(pf[kk], vf, acc_o[dn], 0, 0, 0);
            }
    }

    const size_t pidx = ((size_t)(b * 64 + qt) * nch + ch);
    float* op = Op + pidx * 2048;
    #pragma unroll
    for (int j = 0; j < 4; ++j) {
        const int row = 16 * w + 4 * g + j;
        #pragma unroll
        for (int dn = 0; dn < 4; ++dn)
            op[row * 64 + dn * 16 + r] = acc_o[dn][j];
        if (r == 0) {
            Ml[pidx * 64 + row]      = m4[j];
            Ml[pidx * 64 + 32 + row] = l4[j];
        }
    }
}

// ---------------------------------------------------------------------------
// Combine partials (unchanged).
// ---------------------------------------------------------------------------
__global__ __launch_bounds__(256) void attn_combine_kernel(
    const float* __restrict__ Op, const float* __restrict__ Ml,
    float* __restrict__ out, int tpc, int nch)
{
    const int qt = blockIdx.x;
    const int b  = blockIdx.y;
    const int total64 = qt / 2 + 1;
    const int nact = (total64 + tpc - 1) / tpc;
    const size_t pbase = (size_t)(b * 64 + qt) * nch;

    __shared__ float wgt[8][32];
    __shared__ float linv[32];

    const int tid = threadIdx.x;
    if (tid < 32) {
        float M = -1e30f;
        for (int c = 0; c < nact; ++c)
            M = fmaxf(M, Ml[(pbase + c) * 64 + tid]);
        float L = 0.f;
        for (int c = 0; c < nact; ++c) {
            float wv = exp2f(Ml[(pbase + c) * 64 + tid] - M);
            wgt[c][tid] = wv;
            L += wv * Ml[(pbase + c) * 64 + 32 + tid];
        }
        linv[tid] = 1.0f / L;
    }
    __syncthreads();

    const int d  = tid & 63;
    const int r0 = tid >> 6;
    for (int row = r0; row < 32; row += 4) {
        float a = 0.f;
        for (int c = 0; c < nact; ++c)
            a += wgt[c][row] * Op[(pbase + c) * 2048 + row * 64 + d];
        out[((size_t)b * T_SEQ + qt * 32 + row) * D_HEAD + d] = a * linv[row];
    }
}

extern "C" void kernel_launch(void* const* d_in, const int* in_sizes, int n_in,
                              void* d_out, int out_size, void* d_ws, size_t ws_size,
                              hipStream_t stream) {
    const float* x  = (const float*)d_in[0];
    const float* Wq = (const float*)d_in[1];
    const float* bq = (const float*)d_in[2];
    const float* Wk = (const float*)d_in[3];
    const float* bk = (const float*)d_in[4];
    const float* Wv = (const float*)d_in[5];
    const float* bv = (const float*)d_in[6];
    float* out = (float*)d_out;

    // workspace: q,k,v bf16 (1 MB each), Wp packed (768 KB),
    // attn partials at +4 MB (<=16.5 MB), Cpart at +24 MB (12.6 MB)
    __hip_bfloat16* qb = (__hip_bfloat16*)d_ws;
    __hip_bfloat16* kb = qb + (size_t)NROWS * D_HEAD;
    __hip_bfloat16* vb = kb + (size_t)NROWS * D_HEAD;
    unsigned short* Wp = (unsigned short*)(vb + (size_t)NROWS * D_HEAD);
    float* Op = (float*)((char*)d_ws + (4u << 20));
    float* Cpart = (float*)((char*)d_ws + (24u << 20));

    int nch = 8;
    while (nch > 1 &&
           (24u << 20) + (size_t)2 * NROWS * 192 * 4 > ws_size)
        nch >>= 1;   // ws guard (nch unaffected; keeps legacy fallback shape)
    const int tpc = 32 / nch;   // 64-wide s-tiles per chunk
    float* Ml = Op + (size_t)256 * nch * 2048;

    wcvt_kernel<<<192, 256, 0, stream>>>(Wq, Wk, Wv, Wp);
    proj_part_kernel<<<1024, 256, 0, stream>>>(x, Wp, Cpart);
    proj_fin_kernel<<<NROWS * 48 / 256, 256, 0, stream>>>(Cpart, bq, bk, bv, qb, kb, vb);
    attn_part_kernel<<<dim3(64, nch, B_SZ), 128, 0, stream>>>(qb, kb, vb, Op, Ml, tpc, nch);
    attn_combine_kernel<<<dim3(64, B_SZ), 256, 0, stream>>>(Op, Ml, out, tpc, nch);
}

// Round 15
// 87.459 us; speedup vs baseline: 1.0733x; 1.0733x over previous
//
#include <hip/hip_runtime.h>
#include <hip/hip_bf16.h>

#define T_SEQ 2048
#define E_DIM 2048
#define D_HEAD 64
#define B_SZ 4
#define NROWS (B_SZ * T_SEQ)  // 8192

typedef __attribute__((ext_vector_type(8))) short bf16x8;
typedef __attribute__((ext_vector_type(4))) float f32x4;
typedef __attribute__((ext_vector_type(4))) unsigned short u16x4;
typedef __attribute__((ext_vector_type(8))) unsigned short u16x8;

__device__ __forceinline__ unsigned short f2bf(float x) {
    __hip_bfloat16 h = __float2bfloat16(x);
    return *reinterpret_cast<unsigned short*>(&h);
}

__device__ __forceinline__ u16x8 cvt8(float4 a, float4 b) {
    u16x8 t;
    t[0] = f2bf(a.x); t[1] = f2bf(a.y); t[2] = f2bf(a.z); t[3] = f2bf(a.w);
    t[4] = f2bf(b.x); t[5] = f2bf(b.y); t[6] = f2bf(b.z); t[7] = f2bf(b.w);
    return t;
}

// pack two f32x4 (lo k, hi k) into an MFMA A/B fragment
__device__ __forceinline__ bf16x8 cvtfrag2(f32x4 lo, f32x4 hi) {
    bf16x8 f;
    #pragma unroll
    for (int j = 0; j < 4; ++j) {
        f[j]     = (short)f2bf(lo[j]);
        f[4 + j] = (short)f2bf(hi[j]);
    }
    return f;
}

// MFMA A/B fragment from a [row][k] bf16 buffer: k = base..base+3, base+16..+19
__device__ __forceinline__ bf16x8 ldfrag(const unsigned short* p) {
    u16x4 lo = *(const u16x4*)p;
    u16x4 hi = *(const u16x4*)(p + 16);
    bf16x8 f;
    #pragma unroll
    for (int j = 0; j < 4; ++j) { f[j] = (short)lo[j]; f[4 + j] = (short)hi[j]; }
    return f;
}

// lgkmcnt(0) drain for LDS writes before a raw barrier
__device__ __forceinline__ void lds_fence_barrier() {
    asm volatile("s_waitcnt lgkmcnt(0)" ::: "memory");
    __builtin_amdgcn_s_barrier();
}

// async global -> LDS DMA, 16 bytes per lane (cannot be register-sunk)
__device__ __forceinline__ void gl_lds16(const void* gsrc, void* ldst) {
    __builtin_amdgcn_global_load_lds(
        (const __attribute__((address_space(1))) unsigned int*)(unsigned long long)gsrc,
        (__attribute__((address_space(3))) unsigned int*)(unsigned long long)ldst,
        16, 0, 0);
}

// ---------------------------------------------------------------------------
// W -> bf16 packed in MFMA B-fragment order:
// Wp byte (f*64 + k32)*1024 + l*16 holds lane l's bf16x8 for frag (f, k32);
// f = col/16 in 0..11.
// ---------------------------------------------------------------------------
__global__ __launch_bounds__(256) void wcvt_kernel(
    const float* __restrict__ Wq, const float* __restrict__ Wk,
    const float* __restrict__ Wv, unsigned short* __restrict__ Wp)
{
    const int gid = blockIdx.x * 256 + threadIdx.x;   // 0..49151
    const int l    = gid & 63;
    const int k32  = (gid >> 6) & 63;
    const int f    = gid >> 12;                       // 0..11
    const int r    = l & 15;
    const int g    = l >> 4;
    const int n    = 16 * f + r;                      // 0..191
    const int pj   = n >> 6;
    const int o    = n & 63;
    const float* __restrict__ src = (pj == 0) ? Wq : (pj == 1) ? Wk : Wv;
    const float* p = src + (size_t)o * E_DIM + k32 * 32 + g * 4;
    float4 a = *(const float4*)p;
    float4 b = *(const float4*)(p + 16);
    *(u16x8*)(Wp + (size_t)gid * 8) = cvt8(a, b);
}

// ---------------------------------------------------------------------------
// Fused QKV projection, COUNTED-VMCNT 4-buffer pipeline (round-12 verbatim,
// the best-measured proj config). 256 blocks x 512 thr = 8 waves (2M x 4N).
// Stage tile t+3 via global_load_lds (4 loads/thread), compute tile t,
// s_waitcnt vmcnt(8) (tile t+1 only; t+2/t+3 stay in flight), raw barrier.
// ---------------------------------------------------------------------------
__global__ __launch_bounds__(512) void proj_mfma_kernel(
    const float* __restrict__ x, const unsigned short* __restrict__ Wp,
    const float* __restrict__ bq, const float* __restrict__ bk,
    const float* __restrict__ bv,
    __hip_bfloat16* __restrict__ qb, __hip_bfloat16* __restrict__ kb,
    __hip_bfloat16* __restrict__ vb)
{
    __shared__ unsigned char lds[4][32768];  // per buf: x f32 swz [0,8K), W [8K,32K)

    const int tid  = threadIdx.x;
    const int w    = tid >> 6;
    const int l    = tid & 63;
    const int r    = l & 15;
    const int g    = l >> 4;
    const int wm   = w >> 2;    // 0..1 : 16-row half
    const int wn   = w & 3;     // 0..3 : 48-col slice
    const int row0 = blockIdx.x * 32;

    const int xrow = tid >> 4;
    const int xjl  = (tid & 15) ^ (xrow & 7);
    const unsigned char* xsrc =
        (const unsigned char*)(x + (size_t)(row0 + xrow) * E_DIM + xjl * 4);
    const int xdst = tid * 16;
    const unsigned char* wsrc[3];
    int wdst[3];
    #pragma unroll
    for (int i = 0; i < 3; ++i) {
        const int cw = tid + i * 512;
        const int f  = cw >> 7;
        const int kc = (cw >> 6) & 1;
        const int lw = cw & 63;
        wsrc[i] = (const unsigned char*)Wp + (size_t)(f * 64 + kc) * 1024 + lw * 16;
        wdst[i] = 8192 + cw * 16;
    }

    f32x4 acc[3];
    #pragma unroll
    for (int ff = 0; ff < 3; ++ff) acc[ff] = (f32x4){0.f, 0.f, 0.f, 0.f};

    auto stage = [&](int t, int bi) {
        gl_lds16(xsrc + (size_t)t * 256, &lds[bi][xdst]);
        #pragma unroll
        for (int i = 0; i < 3; ++i)
            gl_lds16(wsrc[i] + (size_t)t * 2048, &lds[bi][wdst[i]]);
    };

    const int arow  = wm * 16 + r;
    const int amask = arow & 7;
    const int abase = arow * 256;

    auto compute = [&](int bi) {
        bf16x8 af[2];
        #pragma unroll
        for (int kk = 0; kk < 2; ++kk) {
            f32x4 lo = *(const f32x4*)&lds[bi][abase + (((kk * 8 + g)     ^ amask) * 16)];
            f32x4 hi = *(const f32x4*)&lds[bi][abase + (((kk * 8 + 4 + g) ^ amask) * 16)];
            af[kk] = cvtfrag2(lo, hi);
        }
        #pragma unroll
        for (int ff = 0; ff < 3; ++ff) {
            const int f = wn * 3 + ff;
            #pragma unroll
            for (int kk = 0; kk < 2; ++kk) {
                bf16x8 bfm = *(const bf16x8*)&lds[bi][8192 + ((f * 2 + kk) * 64 + l) * 16];
                acc[ff] = __builtin_amdgcn_mfma_f32_16x16x32_bf16(af[kk], bfm, acc[ff], 0, 0, 0);
            }
        }
    };

    stage(0, 0);
    stage(1, 1);
    stage(2, 2);
    asm volatile("s_waitcnt vmcnt(8)" ::: "memory");
    __builtin_amdgcn_s_barrier();

    for (int t = 0; t < 29; ++t) {
        stage(t + 3, (t + 3) & 3);
        compute(t & 3);
        asm volatile("s_waitcnt vmcnt(8)" ::: "memory");
        __builtin_amdgcn_s_barrier();
    }
    compute(29 & 3);
    asm volatile("s_waitcnt vmcnt(4)" ::: "memory");
    __builtin_amdgcn_s_barrier();
    compute(30 & 3);
    asm volatile("s_waitcnt vmcnt(0)" ::: "memory");
    __builtin_amdgcn_s_barrier();
    compute(31 & 3);

    #pragma unroll
    for (int ff = 0; ff < 3; ++ff) {
        const int f  = wn * 3 + ff;
        const int n  = 16 * f + r;
        const int pj = n >> 6;
        const int o  = n & 63;
        const float* bias = (pj == 0) ? bq : (pj == 1) ? bk : bv;
        __hip_bfloat16* dst = (pj == 0) ? qb : (pj == 1) ? kb : vb;
        const float scale = (pj == 0) ? 0.18033688011112042f : 1.0f;  // 0.125*log2e
        const float bv_ = bias[o];
        #pragma unroll
        for (int j = 0; j < 4; ++j) {
            const int row = row0 + wm * 16 + 4 * g + j;
            dst[(size_t)row * D_HEAD + o] =
                __float2bfloat16((acc[ff][j] + bv_) * scale);
        }
    }
}

// ---------------------------------------------------------------------------
// Split-KV flash attention partials, QBLK=64: 256 thr = 4 waves, each wave
// owns a 16-row q-slice (w in 0..3). Each staged 64-wide K/V s-tile now
// serves 64 q-rows (2x MFMA amortization, half the staging/barriers).
// Per-wave tile body identical to the verified round-12 version.
// ---------------------------------------------------------------------------
#define LDK 72
#define LDV 68
#define LDP 68

__global__ __launch_bounds__(256) void attn_part_kernel(
    const __hip_bfloat16* __restrict__ qg, const __hip_bfloat16* __restrict__ kg,
    const __hip_bfloat16* __restrict__ vg, float* __restrict__ Op,
    float* __restrict__ Ml, int tpc, int nch)
{
    const int qt = blockIdx.x;          // 0..31 : 64-row q tile
    const int ch = blockIdx.y;
    const int total64 = qt + 1;         // 64-wide s-tiles needed
    if (ch * tpc >= total64) return;

    __shared__ unsigned short Kl[64 * LDK];
    __shared__ unsigned short Vt[64 * LDV];
    __shared__ unsigned short Pl[4 * 16 * LDP];

    const int tid = threadIdx.x;
    const int w   = tid >> 6;           // 0..3
    const int l   = tid & 63;
    const int r   = l & 15;
    const int g   = l >> 4;
    const int q0  = qt * 64;
    const int b   = blockIdx.z;
    const size_t base = (size_t)b * T_SEQ;

    const unsigned short* qb16 = (const unsigned short*)qg;
    const unsigned short* kb16 = (const unsigned short*)kg;
    const unsigned short* vb16 = (const unsigned short*)vg;

    const unsigned short* qrow = qb16 + (base + q0 + 16 * w + r) * D_HEAD;
    bf16x8 qf[2];
    #pragma unroll
    for (int kk = 0; kk < 2; ++kk)
        qf[kk] = ldfrag(qrow + 32 * kk + 4 * g);

    f32x4 acc_o[4];
    #pragma unroll
    for (int dn = 0; dn < 4; ++dn) acc_o[dn] = (f32x4){0.f, 0.f, 0.f, 0.f};
    float m4[4] = {-1e30f, -1e30f, -1e30f, -1e30f};
    float l4[4] = {0.f, 0.f, 0.f, 0.f};

    unsigned short* pw = &Pl[w * 16 * LDP];
    const int ntiles = min(tpc, total64 - ch * tpc);
    const int y = tid & 15, z = tid >> 4;   // V-staging: y=d-group, z 0..15
    const int s0base = ch * tpc * 64;

    // staging registers (tile in flight): 256 threads cover the 64x64 tile
    u16x8 kr[2];
    u16x4 va4[2], vb4[2];

    auto issue = [&](int s0) {
        #pragma unroll
        for (int i = 0; i < 2; ++i) {
            const int c = tid + i * 256;   // 0..511
            kr[i] = *(const u16x8*)(kb16 + (base + s0 + (c >> 3)) * D_HEAD + (c & 7) * 8);
        }
        #pragma unroll
        for (int m = 0; m < 2; ++m) {
            const int sl = 2 * (z + 16 * m);   // even s in 0..62
            const int d0 = y * 4;
            va4[m] = *(const u16x4*)(vb16 + (base + s0 + sl) * D_HEAD + d0);
            vb4[m] = *(const u16x4*)(vb16 + (base + s0 + sl + 1) * D_HEAD + d0);
        }
    };

    issue(s0base);

    for (int it = 0; it < ntiles; ++it) {
        const int s0 = s0base + it * 64;

        __builtin_amdgcn_s_barrier();   // prev tile's LDS reads done

        #pragma unroll
        for (int i = 0; i < 2; ++i) {
            const int c = tid + i * 256;
            *(u16x8*)(&Kl[(c >> 3) * LDK + (c & 7) * 8]) = kr[i];
        }
        #pragma unroll
        for (int m = 0; m < 2; ++m) {
            const int sl = 2 * (z + 16 * m);
            const int d0 = y * 4;
            #pragma unroll
            for (int i = 0; i < 4; ++i) {
                unsigned int pr = (unsigned int)(unsigned short)va4[m][i] |
                                  ((unsigned int)(unsigned short)vb4[m][i] << 16);
                *(unsigned int*)&Vt[(d0 + i) * LDV + sl] = pr;
            }
        }
        lds_fence_barrier();

        if (it + 1 < ntiles) issue(s0 + 64);

        // ---- QK^T: S[16 x 64] per wave ----
        f32x4 s_acc[4];
        #pragma unroll
        for (int nt = 0; nt < 4; ++nt) s_acc[nt] = (f32x4){0.f, 0.f, 0.f, 0.f};
        #pragma unroll
        for (int nt = 0; nt < 4; ++nt)
            #pragma unroll
            for (int kk = 0; kk < 2; ++kk) {
                bf16x8 bf = ldfrag(&Kl[(nt * 16 + r) * LDK + kk * 32 + 4 * g]);
                s_acc[nt] = __builtin_amdgcn_mfma_f32_16x16x32_bf16(qf[kk], bf, s_acc[nt], 0, 0, 0);
            }

        if (s0 + 64 > q0) {  // only the diagonal tile
            #pragma unroll
            for (int nt = 0; nt < 4; ++nt)
                #pragma unroll
                for (int j = 0; j < 4; ++j)
                    if (s0 + nt * 16 + r > q0 + 16 * w + 4 * g + j)
                        s_acc[nt][j] = -1e30f;
        }

        // ---- online softmax (log2 domain) ----
        float tm[4];
        #pragma unroll
        for (int j = 0; j < 4; ++j)
            tm[j] = fmaxf(fmaxf(s_acc[0][j], s_acc[1][j]),
                          fmaxf(s_acc[2][j], s_acc[3][j]));
        #pragma unroll
        for (int mask = 1; mask < 16; mask <<= 1)
            #pragma unroll
            for (int j = 0; j < 4; ++j)
                tm[j] = fmaxf(tm[j], __shfl_xor(tm[j], mask));

        float p[4][4], rs[4];
        #pragma unroll
        for (int j = 0; j < 4; ++j) {
            const float mn = fmaxf(m4[j], tm[j]);
            const float sc = exp2f(m4[j] - mn);
            m4[j] = mn;
            rs[j] = 0.f;
            #pragma unroll
            for (int nt = 0; nt < 4; ++nt) {
                p[nt][j] = exp2f(s_acc[nt][j] - mn);
                rs[j] += p[nt][j];
            }
            l4[j] *= sc;
            acc_o[0][j] *= sc; acc_o[1][j] *= sc;
            acc_o[2][j] *= sc; acc_o[3][j] *= sc;
        }
        #pragma unroll
        for (int mask = 1; mask < 16; mask <<= 1)
            #pragma unroll
            for (int j = 0; j < 4; ++j)
                rs[j] += __shfl_xor(rs[j], mask);
        #pragma unroll
        for (int j = 0; j < 4; ++j) l4[j] += rs[j];

        // ---- P -> LDS bounce (per-wave region) ----
        #pragma unroll
        for (int nt = 0; nt < 4; ++nt)
            #pragma unroll
            for (int j = 0; j < 4; ++j)
                pw[(4 * g + j) * LDP + nt * 16 + r] = f2bf(p[nt][j]);

        bf16x8 pf[2];
        #pragma unroll
        for (int kk = 0; kk < 2; ++kk)
            pf[kk] = ldfrag(&pw[r * LDP + kk * 32 + 4 * g]);

        // ---- PV ----
        #pragma unroll
        for (int dn = 0; dn < 4; ++dn)
            #pragma unroll
            for (int kk = 0; kk < 2; ++kk) {
                bf16x8 vf = ldfrag(&Vt[(dn * 16 + r) * LDV + kk * 32 + 4 * g]);
                acc_o[dn] = __builtin_amdgcn_mfma_f32_16x16x32_bf16(pf[kk], vf, acc_o[dn], 0, 0, 0);
            }
    }

    // write unnormalized partials: 64 rows x 64 cols + (m,l) per row
    const size_t pidx = ((size_t)(b * 32 + qt) * nch + ch);
    float* op = Op + pidx * 4096;
    #pragma unroll
    for (int j = 0; j < 4; ++j) {
        const int row = 16 * w + 4 * g + j;   // 0..63
        #pragma unroll
        for (int dn = 0; dn < 4; ++dn)
            op[row * 64 + dn * 16 + r] = acc_o[dn][j];
        if (r == 0) {
            Ml[pidx * 128 + row]      = m4[j];
            Ml[pidx * 128 + 64 + row] = l4[j];
        }
    }
}

// ---------------------------------------------------------------------------
// Combine partials for 64-row q tiles.
// ---------------------------------------------------------------------------
__global__ __launch_bounds__(256) void attn_combine_kernel(
    const float* __restrict__ Op, const float* __restrict__ Ml,
    float* __restrict__ out, int tpc, int nch)
{
    const int qt = blockIdx.x;   // 0..31
    const int b  = blockIdx.y;
    const int total64 = qt + 1;
    const int nact = (total64 + tpc - 1) / tpc;
    const size_t pbase = (size_t)(b * 32 + qt) * nch;

    __shared__ float wgt[8][64];
    __shared__ float linv[64];

    const int tid = threadIdx.x;
    if (tid < 64) {
        float M = -1e30f;
        for (int c = 0; c < nact; ++c)
            M = fmaxf(M, Ml[(pbase + c) * 128 + tid]);
        float L = 0.f;
        for (int c = 0; c < nact; ++c) {
            float wv = exp2f(Ml[(pbase + c) * 128 + tid] - M);
            wgt[c][tid] = wv;
            L += wv * Ml[(pbase + c) * 128 + 64 + tid];
        }
        linv[tid] = 1.0f / L;
    }
    __syncthreads();

    const int d  = tid & 63;
    const int r0 = tid >> 6;
    for (int row = r0; row < 64; row += 4) {
        float a = 0.f;
        for (int c = 0; c < nact; ++c)
            a += wgt[c][row] * Op[(pbase + c) * 4096 + row * 64 + d];
        out[((size_t)b * T_SEQ + qt * 64 + row) * D_HEAD + d] = a * linv[row];
    }
}

extern "C" void kernel_launch(void* const* d_in, const int* in_sizes, int n_in,
                              void* d_out, int out_size, void* d_ws, size_t ws_size,
                              hipStream_t stream) {
    const float* x  = (const float*)d_in[0];
    const float* Wq = (const float*)d_in[1];
    const float* bq = (const float*)d_in[2];
    const float* Wk = (const float*)d_in[3];
    const float* bk = (const float*)d_in[4];
    const float* Wv = (const float*)d_in[5];
    const float* bv = (const float*)d_in[6];
    float* out = (float*)d_out;

    // workspace: q,k,v bf16 (1 MB each), Wp packed (768 KB), partials at +4 MB
    __hip_bfloat16* qb = (__hip_bfloat16*)d_ws;
    __hip_bfloat16* kb = qb + (size_t)NROWS * D_HEAD;
    __hip_bfloat16* vb = kb + (size_t)NROWS * D_HEAD;
    unsigned short* Wp = (unsigned short*)(vb + (size_t)NROWS * D_HEAD);
    float* Op = (float*)((char*)d_ws + (4u << 20));

    int nch = 8;
    while (nch > 1 &&
           (4u << 20) + (size_t)128 * nch * (4096 + 128) * 4 > ws_size)
        nch >>= 1;
    const int tpc = 32 / nch;   // 64-wide s-tiles per chunk
    float* Ml = Op + (size_t)128 * nch * 4096;

    wcvt_kernel<<<192, 256, 0, stream>>>(Wq, Wk, Wv, Wp);
    proj_mfma_kernel<<<NROWS / 32, 512, 0, stream>>>(x, Wp, bq, bk, bv, qb, kb, vb);
    attn_part_kernel<<<dim3(32, nch, B_SZ), 256, 0, stream>>>(qb, kb, vb, Op, Ml, tpc, nch);
    attn_combine_kernel<<<dim3(32, B_SZ), 256, 0, stream>>>(Op, Ml, out, tpc, nch);
}

// Round 16
// 67.549 us; speedup vs baseline: 1.3897x; 1.2947x over previous
//
#include <hip/hip_runtime.h>
#include <hip/hip_bf16.h>

#define T_SEQ 2048
#define E_DIM 2048
#define D_HEAD 64
#define B_SZ 4
#define NROWS (B_SZ * T_SEQ)  // 8192

typedef __attribute__((ext_vector_type(8))) short bf16x8;
typedef __attribute__((ext_vector_type(4))) float f32x4;
typedef __attribute__((ext_vector_type(4))) unsigned short u16x4;
typedef __attribute__((ext_vector_type(8))) unsigned short u16x8;

__device__ __forceinline__ unsigned short f2bf(float x) {
    __hip_bfloat16 h = __float2bfloat16(x);
    return *reinterpret_cast<unsigned short*>(&h);
}

__device__ __forceinline__ u16x8 cvt8(float4 a, float4 b) {
    u16x8 t;
    t[0] = f2bf(a.x); t[1] = f2bf(a.y); t[2] = f2bf(a.z); t[3] = f2bf(a.w);
    t[4] = f2bf(b.x); t[5] = f2bf(b.y); t[6] = f2bf(b.z); t[7] = f2bf(b.w);
    return t;
}

// pack two f32x4 (lo k, hi k) into an MFMA A/B fragment
__device__ __forceinline__ bf16x8 cvtfrag2(f32x4 lo, f32x4 hi) {
    bf16x8 f;
    #pragma unroll
    for (int j = 0; j < 4; ++j) {
        f[j]     = (short)f2bf(lo[j]);
        f[4 + j] = (short)f2bf(hi[j]);
    }
    return f;
}

// MFMA A/B fragment from a [row][k] bf16 buffer: k = base..base+3, base+16..+19
__device__ __forceinline__ bf16x8 ldfrag(const unsigned short* p) {
    u16x4 lo = *(const u16x4*)p;
    u16x4 hi = *(const u16x4*)(p + 16);
    bf16x8 f;
    #pragma unroll
    for (int j = 0; j < 4; ++j) { f[j] = (short)lo[j]; f[4 + j] = (short)hi[j]; }
    return f;
}

// lgkmcnt(0) drain for LDS writes before a raw barrier
__device__ __forceinline__ void lds_fence_barrier() {
    asm volatile("s_waitcnt lgkmcnt(0)" ::: "memory");
    __builtin_amdgcn_s_barrier();
}

// async global -> LDS DMA, 16 bytes per lane (cannot be register-sunk)
__device__ __forceinline__ void gl_lds16(const void* gsrc, void* ldst) {
    __builtin_amdgcn_global_load_lds(
        (const __attribute__((address_space(1))) unsigned int*)(unsigned long long)gsrc,
        (__attribute__((address_space(3))) unsigned int*)(unsigned long long)ldst,
        16, 0, 0);
}

// ---------------------------------------------------------------------------
// W -> bf16 packed in MFMA B-fragment order:
// Wp byte (f*64 + k32)*1024 + l*16 holds lane l's bf16x8 for frag (f, k32);
// f = col/16 in 0..11.
// ---------------------------------------------------------------------------
__global__ __launch_bounds__(256) void wcvt_kernel(
    const float* __restrict__ Wq, const float* __restrict__ Wk,
    const float* __restrict__ Wv, unsigned short* __restrict__ Wp)
{
    const int gid = blockIdx.x * 256 + threadIdx.x;   // 0..49151
    const int l    = gid & 63;
    const int k32  = (gid >> 6) & 63;
    const int f    = gid >> 12;                       // 0..11
    const int r    = l & 15;
    const int g    = l >> 4;
    const int n    = 16 * f + r;                      // 0..191
    const int pj   = n >> 6;
    const int o    = n & 63;
    const float* __restrict__ src = (pj == 0) ? Wq : (pj == 1) ? Wk : Wv;
    const float* p = src + (size_t)o * E_DIM + k32 * 32 + g * 4;
    float4 a = *(const float4*)p;
    float4 b = *(const float4*)(p + 16);
    *(u16x8*)(Wp + (size_t)gid * 8) = cvt8(a, b);
}

// ---------------------------------------------------------------------------
// Fused QKV projection, COUNTED-VMCNT 4-buffer pipeline (round-12 verbatim,
// best-measured proj config). 256 blocks x 512 thr = 8 waves (2M x 4N).
// Stage tile t+3 via global_load_lds (4 loads/thread), compute tile t,
// s_waitcnt vmcnt(8) (tile t+1 only; t+2/t+3 stay in flight), raw barrier.
// ---------------------------------------------------------------------------
__global__ __launch_bounds__(512) void proj_mfma_kernel(
    const float* __restrict__ x, const unsigned short* __restrict__ Wp,
    const float* __restrict__ bq, const float* __restrict__ bk,
    const float* __restrict__ bv,
    __hip_bfloat16* __restrict__ qb, __hip_bfloat16* __restrict__ kb,
    __hip_bfloat16* __restrict__ vb)
{
    __shared__ unsigned char lds[4][32768];  // per buf: x f32 swz [0,8K), W [8K,32K)

    const int tid  = threadIdx.x;
    const int w    = tid >> 6;
    const int l    = tid & 63;
    const int r    = l & 15;
    const int g    = l >> 4;
    const int wm   = w >> 2;    // 0..1 : 16-row half
    const int wn   = w & 3;     // 0..3 : 48-col slice
    const int row0 = blockIdx.x * 32;

    const int xrow = tid >> 4;
    const int xjl  = (tid & 15) ^ (xrow & 7);
    const unsigned char* xsrc =
        (const unsigned char*)(x + (size_t)(row0 + xrow) * E_DIM + xjl * 4);
    const int xdst = tid * 16;
    const unsigned char* wsrc[3];
    int wdst[3];
    #pragma unroll
    for (int i = 0; i < 3; ++i) {
        const int cw = tid + i * 512;
        const int f  = cw >> 7;
        const int kc = (cw >> 6) & 1;
        const int lw = cw & 63;
        wsrc[i] = (const unsigned char*)Wp + (size_t)(f * 64 + kc) * 1024 + lw * 16;
        wdst[i] = 8192 + cw * 16;
    }

    f32x4 acc[3];
    #pragma unroll
    for (int ff = 0; ff < 3; ++ff) acc[ff] = (f32x4){0.f, 0.f, 0.f, 0.f};

    auto stage = [&](int t, int bi) {
        gl_lds16(xsrc + (size_t)t * 256, &lds[bi][xdst]);
        #pragma unroll
        for (int i = 0; i < 3; ++i)
            gl_lds16(wsrc[i] + (size_t)t * 2048, &lds[bi][wdst[i]]);
    };

    const int arow  = wm * 16 + r;
    const int amask = arow & 7;
    const int abase = arow * 256;

    auto compute = [&](int bi) {
        bf16x8 af[2];
        #pragma unroll
        for (int kk = 0; kk < 2; ++kk) {
            f32x4 lo = *(const f32x4*)&lds[bi][abase + (((kk * 8 + g)     ^ amask) * 16)];
            f32x4 hi = *(const f32x4*)&lds[bi][abase + (((kk * 8 + 4 + g) ^ amask) * 16)];
            af[kk] = cvtfrag2(lo, hi);
        }
        #pragma unroll
        for (int ff = 0; ff < 3; ++ff) {
            const int f = wn * 3 + ff;
            #pragma unroll
            for (int kk = 0; kk < 2; ++kk) {
                bf16x8 bfm = *(const bf16x8*)&lds[bi][8192 + ((f * 2 + kk) * 64 + l) * 16];
                acc[ff] = __builtin_amdgcn_mfma_f32_16x16x32_bf16(af[kk], bfm, acc[ff], 0, 0, 0);
            }
        }
    };

    stage(0, 0);
    stage(1, 1);
    stage(2, 2);
    asm volatile("s_waitcnt vmcnt(8)" ::: "memory");
    __builtin_amdgcn_s_barrier();

    for (int t = 0; t < 29; ++t) {
        stage(t + 3, (t + 3) & 3);
        compute(t & 3);
        asm volatile("s_waitcnt vmcnt(8)" ::: "memory");
        __builtin_amdgcn_s_barrier();
    }
    compute(29 & 3);
    asm volatile("s_waitcnt vmcnt(4)" ::: "memory");
    __builtin_amdgcn_s_barrier();
    compute(30 & 3);
    asm volatile("s_waitcnt vmcnt(0)" ::: "memory");
    __builtin_amdgcn_s_barrier();
    compute(31 & 3);

    #pragma unroll
    for (int ff = 0; ff < 3; ++ff) {
        const int f  = wn * 3 + ff;
        const int n  = 16 * f + r;
        const int pj = n >> 6;
        const int o  = n & 63;
        const float* bias = (pj == 0) ? bq : (pj == 1) ? bk : bv;
        __hip_bfloat16* dst = (pj == 0) ? qb : (pj == 1) ? kb : vb;
        const float scale = (pj == 0) ? 0.18033688011112042f : 1.0f;  // 0.125*log2e
        const float bv_ = bias[o];
        #pragma unroll
        for (int j = 0; j < 4; ++j) {
            const int row = row0 + wm * 16 + 4 * g + j;
            dst[(size_t)row * D_HEAD + o] =
                __float2bfloat16((acc[ff][j] + bv_) * scale);
        }
    }
}

// ---------------------------------------------------------------------------
// Split-KV flash attention partials (round-12 structure: 128 thr = 2 waves,
// 32 q-rows, s-tile 64, T14 async-stage) + T5 s_setprio around MFMA clusters
// (multi-block/CU wave-role diversity -> scheduler favors MFMA waves; +4-7%
// measured on attn in this regime, null only for lockstep 1-block/CU GEMM).
// ---------------------------------------------------------------------------
#define LDK 72
#define LDV 68
#define LDP 68

__global__ __launch_bounds__(128) void attn_part_kernel(
    const __hip_bfloat16* __restrict__ qg, const __hip_bfloat16* __restrict__ kg,
    const __hip_bfloat16* __restrict__ vg, float* __restrict__ Op,
    float* __restrict__ Ml, int tpc, int nch)
{
    const int qt = blockIdx.x;
    const int ch = blockIdx.y;
    const int total64 = qt / 2 + 1;
    if (ch * tpc >= total64) return;

    __shared__ unsigned short Kl[64 * LDK];
    __shared__ unsigned short Vt[64 * LDV];
    __shared__ unsigned short Pl[2 * 16 * LDP];

    const int tid = threadIdx.x;
    const int w   = tid >> 6;
    const int l   = tid & 63;
    const int r   = l & 15;
    const int g   = l >> 4;
    const int q0  = qt * 32;
    const int b   = blockIdx.z;
    const size_t base = (size_t)b * T_SEQ;

    const unsigned short* qb16 = (const unsigned short*)qg;
    const unsigned short* kb16 = (const unsigned short*)kg;
    const unsigned short* vb16 = (const unsigned short*)vg;

    const unsigned short* qrow = qb16 + (base + q0 + 16 * w + r) * D_HEAD;
    bf16x8 qf[2];
    #pragma unroll
    for (int kk = 0; kk < 2; ++kk)
        qf[kk] = ldfrag(qrow + 32 * kk + 4 * g);

    f32x4 acc_o[4];
    #pragma unroll
    for (int dn = 0; dn < 4; ++dn) acc_o[dn] = (f32x4){0.f, 0.f, 0.f, 0.f};
    float m4[4] = {-1e30f, -1e30f, -1e30f, -1e30f};
    float l4[4] = {0.f, 0.f, 0.f, 0.f};

    unsigned short* pw = &Pl[w * 16 * LDP];
    const int ntiles = min(tpc, total64 - ch * tpc);
    const int y = tid & 15, z = tid >> 4;   // V-staging coords
    const int s0base = ch * tpc * 64;

    u16x8 kr[4];
    u16x4 va4[4], vb4[4];

    auto issue = [&](int s0) {
        #pragma unroll
        for (int i = 0; i < 4; ++i) {
            const int c = tid + i * 128;
            kr[i] = *(const u16x8*)(kb16 + (base + s0 + (c >> 3)) * D_HEAD + (c & 7) * 8);
        }
        #pragma unroll
        for (int m = 0; m < 4; ++m) {
            const int sl = 2 * (z + 8 * m);
            const int d0 = y * 4;
            va4[m] = *(const u16x4*)(vb16 + (base + s0 + sl) * D_HEAD + d0);
            vb4[m] = *(const u16x4*)(vb16 + (base + s0 + sl + 1) * D_HEAD + d0);
        }
    };

    issue(s0base);

    for (int it = 0; it < ntiles; ++it) {
        const int s0 = s0base + it * 64;

        __builtin_amdgcn_s_barrier();   // prev tile's LDS reads done

        #pragma unroll
        for (int i = 0; i < 4; ++i) {
            const int c = tid + i * 128;
            *(u16x8*)(&Kl[(c >> 3) * LDK + (c & 7) * 8]) = kr[i];
        }
        #pragma unroll
        for (int m = 0; m < 4; ++m) {
            const int sl = 2 * (z + 8 * m);
            const int d0 = y * 4;
            #pragma unroll
            for (int i = 0; i < 4; ++i) {
                unsigned int pr = (unsigned int)(unsigned short)va4[m][i] |
                                  ((unsigned int)(unsigned short)vb4[m][i] << 16);
                *(unsigned int*)&Vt[(d0 + i) * LDV + sl] = pr;
            }
        }
        lds_fence_barrier();

        if (it + 1 < ntiles) issue(s0 + 64);

        // ---- QK^T: S[16 x 64] per wave ----
        f32x4 s_acc[4];
        #pragma unroll
        for (int nt = 0; nt < 4; ++nt) s_acc[nt] = (f32x4){0.f, 0.f, 0.f, 0.f};
        __builtin_amdgcn_s_setprio(1);
        #pragma unroll
        for (int nt = 0; nt < 4; ++nt)
            #pragma unroll
            for (int kk = 0; kk < 2; ++kk) {
                bf16x8 bf = ldfrag(&Kl[(nt * 16 + r) * LDK + kk * 32 + 4 * g]);
                s_acc[nt] = __builtin_amdgcn_mfma_f32_16x16x32_bf16(qf[kk], bf, s_acc[nt], 0, 0, 0);
            }
        __builtin_amdgcn_s_setprio(0);

        if (s0 + 64 > q0) {
            #pragma unroll
            for (int nt = 0; nt < 4; ++nt)
                #pragma unroll
                for (int j = 0; j < 4; ++j)
                    if (s0 + nt * 16 + r > q0 + 16 * w + 4 * g + j)
                        s_acc[nt][j] = -1e30f;
        }

        // ---- online softmax (log2 domain) ----
        float tm[4];
        #pragma unroll
        for (int j = 0; j < 4; ++j)
            tm[j] = fmaxf(fmaxf(s_acc[0][j], s_acc[1][j]),
                          fmaxf(s_acc[2][j], s_acc[3][j]));
        #pragma unroll
        for (int mask = 1; mask < 16; mask <<= 1)
            #pragma unroll
            for (int j = 0; j < 4; ++j)
                tm[j] = fmaxf(tm[j], __shfl_xor(tm[j], mask));

        float p[4][4], rs[4];
        #pragma unroll
        for (int j = 0; j < 4; ++j) {
            const float mn = fmaxf(m4[j], tm[j]);
            const float sc = exp2f(m4[j] - mn);
            m4[j] = mn;
            rs[j] = 0.f;
            #pragma unroll
            for (int nt = 0; nt < 4; ++nt) {
                p[nt][j] = exp2f(s_acc[nt][j] - mn);
                rs[j] += p[nt][j];
            }
            l4[j] *= sc;
            acc_o[0][j] *= sc; acc_o[1][j] *= sc;
            acc_o[2][j] *= sc; acc_o[3][j] *= sc;
        }
        #pragma unroll
        for (int mask = 1; mask < 16; mask <<= 1)
            #pragma unroll
            for (int j = 0; j < 4; ++j)
                rs[j] += __shfl_xor(rs[j], mask);
        #pragma unroll
        for (int j = 0; j < 4; ++j) l4[j] += rs[j];

        // ---- P -> LDS bounce (per-wave region) ----
        #pragma unroll
        for (int nt = 0; nt < 4; ++nt)
            #pragma unroll
            for (int j = 0; j < 4; ++j)
                pw[(4 * g + j) * LDP + nt * 16 + r] = f2bf(p[nt][j]);

        bf16x8 pf[2];
        #pragma unroll
        for (int kk = 0; kk < 2; ++kk)
            pf[kk] = ldfrag(&pw[r * LDP + kk * 32 + 4 * g]);

        // ---- PV: O[16 x 64] += P[16 x 64] * V[64 x 64] ----
        __builtin_amdgcn_s_setprio(1);
        #pragma unroll
        for (int dn = 0; dn < 4; ++dn)
            #pragma unroll
            for (int kk = 0; kk < 2; ++kk) {
                bf16x8 vf = ldfrag(&Vt[(dn * 16 + r) * LDV + kk * 32 + 4 * g]);
                acc_o[dn] = __builtin_amdgcn_mfma_f32_16x16x32_bf16(pf[kk], vf, acc_o[dn], 0, 0, 0);
            }
        __builtin_amdgcn_s_setprio(0);
    }

    const size_t pidx = ((size_t)(b * 64 + qt) * nch + ch);
    float* op = Op + pidx * 2048;
    #pragma unroll
    for (int j = 0; j < 4; ++j) {
        const int row = 16 * w + 4 * g + j;
        #pragma unroll
        for (int dn = 0; dn < 4; ++dn)
            op[row * 64 + dn * 16 + r] = acc_o[dn][j];
        if (r == 0) {
            Ml[pidx * 64 + row]      = m4[j];
            Ml[pidx * 64 + 32 + row] = l4[j];
        }
    }
}

// ---------------------------------------------------------------------------
// Combine partials (round-12 verbatim).
// ---------------------------------------------------------------------------
__global__ __launch_bounds__(256) void attn_combine_kernel(
    const float* __restrict__ Op, const float* __restrict__ Ml,
    float* __restrict__ out, int tpc, int nch)
{
    const int qt = blockIdx.x;
    const int b  = blockIdx.y;
    const int total64 = qt / 2 + 1;
    const int nact = (total64 + tpc - 1) / tpc;
    const size_t pbase = (size_t)(b * 64 + qt) * nch;

    __shared__ float wgt[8][32];
    __shared__ float linv[32];

    const int tid = threadIdx.x;
    if (tid < 32) {
        float M = -1e30f;
        for (int c = 0; c < nact; ++c)
            M = fmaxf(M, Ml[(pbase + c) * 64 + tid]);
        float L = 0.f;
        for (int c = 0; c < nact; ++c) {
            float wv = exp2f(Ml[(pbase + c) * 64 + tid] - M);
            wgt[c][tid] = wv;
            L += wv * Ml[(pbase + c) * 64 + 32 + tid];
        }
        linv[tid] = 1.0f / L;
    }
    __syncthreads();

    const int d  = tid & 63;
    const int r0 = tid >> 6;
    for (int row = r0; row < 32; row += 4) {
        float a = 0.f;
        for (int c = 0; c < nact; ++c)
            a += wgt[c][row] * Op[(pbase + c) * 2048 + row * 64 + d];
        out[((size_t)b * T_SEQ + qt * 32 + row) * D_HEAD + d] = a * linv[row];
    }
}

extern "C" void kernel_launch(void* const* d_in, const int* in_sizes, int n_in,
                              void* d_out, int out_size, void* d_ws, size_t ws_size,
                              hipStream_t stream) {
    const float* x  = (const float*)d_in[0];
    const float* Wq = (const float*)d_in[1];
    const float* bq = (const float*)d_in[2];
    const float* Wk = (const float*)d_in[3];
    const float* bk = (const float*)d_in[4];
    const float* Wv = (const float*)d_in[5];
    const float* bv = (const float*)d_in[6];
    float* out = (float*)d_out;

    // workspace: q,k,v bf16 (1 MB each), Wp packed (768 KB), partials at +4 MB
    __hip_bfloat16* qb = (__hip_bfloat16*)d_ws;
    __hip_bfloat16* kb = qb + (size_t)NROWS * D_HEAD;
    __hip_bfloat16* vb = kb + (size_t)NROWS * D_HEAD;
    unsigned short* Wp = (unsigned short*)(vb + (size_t)NROWS * D_HEAD);
    float* Op = (float*)((char*)d_ws + (4u << 20));

    int nch = 8;
    while (nch > 1 &&
           (4u << 20) + (size_t)256 * nch * (2048 + 64) * 4 > ws_size)
        nch >>= 1;
    const int tpc = 32 / nch;   // 64-wide s-tiles per chunk
    float* Ml = Op + (size_t)256 * nch * 2048;

    wcvt_kernel<<<192, 256, 0, stream>>>(Wq, Wk, Wv, Wp);
    proj_mfma_kernel<<<NROWS / 32, 512, 0, stream>>>(x, Wp, bq, bk, bv, qb, kb, vb);
    attn_part_kernel<<<dim3(64, nch, B_SZ), 128, 0, stream>>>(qb, kb, vb, Op, Ml, tpc, nch);
    attn_combine_kernel<<<dim3(64, B_SZ), 256, 0, stream>>>(Op, Ml, out, tpc, nch);
}

// Round 17
// 63.589 us; speedup vs baseline: 1.4762x; 1.0623x over previous
//
#include <hip/hip_runtime.h>
#include <hip/hip_bf16.h>

#define T_SEQ 2048
#define E_DIM 2048
#define D_HEAD 64
#define B_SZ 4
#define NROWS (B_SZ * T_SEQ)  // 8192

typedef __attribute__((ext_vector_type(8))) short bf16x8;
typedef __attribute__((ext_vector_type(4))) float f32x4;
typedef __attribute__((ext_vector_type(4))) unsigned short u16x4;
typedef __attribute__((ext_vector_type(8))) unsigned short u16x8;

__device__ __forceinline__ unsigned short f2bf(float x) {
    __hip_bfloat16 h = __float2bfloat16(x);
    return *reinterpret_cast<unsigned short*>(&h);
}

__device__ __forceinline__ u16x8 cvt8(float4 a, float4 b) {
    u16x8 t;
    t[0] = f2bf(a.x); t[1] = f2bf(a.y); t[2] = f2bf(a.z); t[3] = f2bf(a.w);
    t[4] = f2bf(b.x); t[5] = f2bf(b.y); t[6] = f2bf(b.z); t[7] = f2bf(b.w);
    return t;
}

// pack two f32x4 (lo k, hi k) into an MFMA A/B fragment
__device__ __forceinline__ bf16x8 cvtfrag2(f32x4 lo, f32x4 hi) {
    bf16x8 f;
    #pragma unroll
    for (int j = 0; j < 4; ++j) {
        f[j]     = (short)f2bf(lo[j]);
        f[4 + j] = (short)f2bf(hi[j]);
    }
    return f;
}

// MFMA A/B fragment from a [row][k] bf16 buffer: k = base..base+3, base+16..+19
__device__ __forceinline__ bf16x8 ldfrag(const unsigned short* p) {
    u16x4 lo = *(const u16x4*)p;
    u16x4 hi = *(const u16x4*)(p + 16);
    bf16x8 f;
    #pragma unroll
    for (int j = 0; j < 4; ++j) { f[j] = (short)lo[j]; f[4 + j] = (short)hi[j]; }
    return f;
}

// lgkmcnt(0) drain for LDS writes before a raw barrier
__device__ __forceinline__ void lds_fence_barrier() {
    asm volatile("s_waitcnt lgkmcnt(0)" ::: "memory");
    __builtin_amdgcn_s_barrier();
}

// async global -> LDS DMA, 16 bytes per lane (cannot be register-sunk)
__device__ __forceinline__ void gl_lds16(const void* gsrc, void* ldst) {
    __builtin_amdgcn_global_load_lds(
        (const __attribute__((address_space(1))) unsigned int*)(unsigned long long)gsrc,
        (__attribute__((address_space(3))) unsigned int*)(unsigned long long)ldst,
        16, 0, 0);
}

// ---------------------------------------------------------------------------
// W -> bf16 packed in MFMA B-fragment order:
// Wp byte (f*64 + k32)*1024 + l*16 holds lane l's bf16x8 for frag (f, k32);
// f = col/16 in 0..11.
// ---------------------------------------------------------------------------
__global__ __launch_bounds__(256) void wcvt_kernel(
    const float* __restrict__ Wq, const float* __restrict__ Wk,
    const float* __restrict__ Wv, unsigned short* __restrict__ Wp)
{
    const int gid = blockIdx.x * 256 + threadIdx.x;   // 0..49151
    const int l    = gid & 63;
    const int k32  = (gid >> 6) & 63;
    const int f    = gid >> 12;                       // 0..11
    const int r    = l & 15;
    const int g    = l >> 4;
    const int n    = 16 * f + r;                      // 0..191
    const int pj   = n >> 6;
    const int o    = n & 63;
    const float* __restrict__ src = (pj == 0) ? Wq : (pj == 1) ? Wk : Wv;
    const float* p = src + (size_t)o * E_DIM + k32 * 32 + g * 4;
    float4 a = *(const float4*)p;
    float4 b = *(const float4*)(p + 16);
    *(u16x8*)(Wp + (size_t)gid * 8) = cvt8(a, b);
}

// ---------------------------------------------------------------------------
// Fused QKV projection, COUNTED-VMCNT 4-buffer pipeline + PER-BLOCK K-PHASE
// ROTATION. Block bid processes K-tiles in order (t + bid) & 31, so at any
// instant the 256 blocks read 32 DIFFERENT byte-columns of x -> accesses
// spread over all HBM channels instead of concentrating on one congruence
// class mod 8KB (the hypothesized cause of the universal ~0.92 TB/s wall).
// Structure otherwise round-12 verbatim: 256 blocks x 512 thr = 8 waves,
// stage tile via global_load_lds (4 loads/thread), vmcnt(8), raw barrier.
// ---------------------------------------------------------------------------
__global__ __launch_bounds__(512) void proj_mfma_kernel(
    const float* __restrict__ x, const unsigned short* __restrict__ Wp,
    const float* __restrict__ bq, const float* __restrict__ bk,
    const float* __restrict__ bv,
    __hip_bfloat16* __restrict__ qb, __hip_bfloat16* __restrict__ kb,
    __hip_bfloat16* __restrict__ vb)
{
    __shared__ unsigned char lds[4][32768];  // per buf: x f32 swz [0,8K), W [8K,32K)

    const int tid  = threadIdx.x;
    const int w    = tid >> 6;
    const int l    = tid & 63;
    const int r    = l & 15;
    const int g    = l >> 4;
    const int wm   = w >> 2;    // 0..1 : 16-row half
    const int wn   = w & 3;     // 0..3 : 48-col slice
    const int row0 = blockIdx.x * 32;
    const int phase = blockIdx.x & 31;   // K-phase rotation

    const int xrow = tid >> 4;
    const int xjl  = (tid & 15) ^ (xrow & 7);
    const unsigned char* xsrc =
        (const unsigned char*)(x + (size_t)(row0 + xrow) * E_DIM + xjl * 4);
    const int xdst = tid * 16;
    const unsigned char* wsrc[3];
    int wdst[3];
    #pragma unroll
    for (int i = 0; i < 3; ++i) {
        const int cw = tid + i * 512;
        const int f  = cw >> 7;
        const int kc = (cw >> 6) & 1;
        const int lw = cw & 63;
        wsrc[i] = (const unsigned char*)Wp + (size_t)(f * 64 + kc) * 1024 + lw * 16;
        wdst[i] = 8192 + cw * 16;
    }

    f32x4 acc[3];
    #pragma unroll
    for (int ff = 0; ff < 3; ++ff) acc[ff] = (f32x4){0.f, 0.f, 0.f, 0.f};

    // stage K-tile tt (absolute) into buffer bi
    auto stage = [&](int tt, int bi) {
        gl_lds16(xsrc + (size_t)tt * 256, &lds[bi][xdst]);
        #pragma unroll
        for (int i = 0; i < 3; ++i)
            gl_lds16(wsrc[i] + (size_t)tt * 2048, &lds[bi][wdst[i]]);
    };

    const int arow  = wm * 16 + r;
    const int amask = arow & 7;
    const int abase = arow * 256;

    auto compute = [&](int bi) {
        bf16x8 af[2];
        #pragma unroll
        for (int kk = 0; kk < 2; ++kk) {
            f32x4 lo = *(const f32x4*)&lds[bi][abase + (((kk * 8 + g)     ^ amask) * 16)];
            f32x4 hi = *(const f32x4*)&lds[bi][abase + (((kk * 8 + 4 + g) ^ amask) * 16)];
            af[kk] = cvtfrag2(lo, hi);
        }
        #pragma unroll
        for (int ff = 0; ff < 3; ++ff) {
            const int f = wn * 3 + ff;
            #pragma unroll
            for (int kk = 0; kk < 2; ++kk) {
                bf16x8 bfm = *(const bf16x8*)&lds[bi][8192 + ((f * 2 + kk) * 64 + l) * 16];
                acc[ff] = __builtin_amdgcn_mfma_f32_16x16x32_bf16(af[kk], bfm, acc[ff], 0, 0, 0);
            }
        }
    };

    stage((0 + phase) & 31, 0);
    stage((1 + phase) & 31, 1);
    stage((2 + phase) & 31, 2);
    asm volatile("s_waitcnt vmcnt(8)" ::: "memory");
    __builtin_amdgcn_s_barrier();

    for (int t = 0; t < 29; ++t) {
        stage((t + 3 + phase) & 31, (t + 3) & 3);
        compute(t & 3);
        asm volatile("s_waitcnt vmcnt(8)" ::: "memory");
        __builtin_amdgcn_s_barrier();
    }
    compute(29 & 3);
    asm volatile("s_waitcnt vmcnt(4)" ::: "memory");
    __builtin_amdgcn_s_barrier();
    compute(30 & 3);
    asm volatile("s_waitcnt vmcnt(0)" ::: "memory");
    __builtin_amdgcn_s_barrier();
    compute(31 & 3);

    #pragma unroll
    for (int ff = 0; ff < 3; ++ff) {
        const int f  = wn * 3 + ff;
        const int n  = 16 * f + r;
        const int pj = n >> 6;
        const int o  = n & 63;
        const float* bias = (pj == 0) ? bq : (pj == 1) ? bk : bv;
        __hip_bfloat16* dst = (pj == 0) ? qb : (pj == 1) ? kb : vb;
        const float scale = (pj == 0) ? 0.18033688011112042f : 1.0f;  // 0.125*log2e
        const float bv_ = bias[o];
        #pragma unroll
        for (int j = 0; j < 4; ++j) {
            const int row = row0 + wm * 16 + 4 * g + j;
            dst[(size_t)row * D_HEAD + o] =
                __float2bfloat16((acc[ff][j] + bv_) * scale);
        }
    }
}

// ---------------------------------------------------------------------------
// Split-KV flash attention partials (round-16 verbatim: 128 thr = 2 waves,
// 32 q-rows, s-tile 64, T14 async-stage, T5 setprio around MFMA clusters).
// ---------------------------------------------------------------------------
#define LDK 72
#define LDV 68
#define LDP 68

__global__ __launch_bounds__(128) void attn_part_kernel(
    const __hip_bfloat16* __restrict__ qg, const __hip_bfloat16* __restrict__ kg,
    const __hip_bfloat16* __restrict__ vg, float* __restrict__ Op,
    float* __restrict__ Ml, int tpc, int nch)
{
    const int qt = blockIdx.x;
    const int ch = blockIdx.y;
    const int total64 = qt / 2 + 1;
    if (ch * tpc >= total64) return;

    __shared__ unsigned short Kl[64 * LDK];
    __shared__ unsigned short Vt[64 * LDV];
    __shared__ unsigned short Pl[2 * 16 * LDP];

    const int tid = threadIdx.x;
    const int w   = tid >> 6;
    const int l   = tid & 63;
    const int r   = l & 15;
    const int g   = l >> 4;
    const int q0  = qt * 32;
    const int b   = blockIdx.z;
    const size_t base = (size_t)b * T_SEQ;

    const unsigned short* qb16 = (const unsigned short*)qg;
    const unsigned short* kb16 = (const unsigned short*)kg;
    const unsigned short* vb16 = (const unsigned short*)vg;

    const unsigned short* qrow = qb16 + (base + q0 + 16 * w + r) * D_HEAD;
    bf16x8 qf[2];
    #pragma unroll
    for (int kk = 0; kk < 2; ++kk)
        qf[kk] = ldfrag(qrow + 32 * kk + 4 * g);

    f32x4 acc_o[4];
    #pragma unroll
    for (int dn = 0; dn < 4; ++dn) acc_o[dn] = (f32x4){0.f, 0.f, 0.f, 0.f};
    float m4[4] = {-1e30f, -1e30f, -1e30f, -1e30f};
    float l4[4] = {0.f, 0.f, 0.f, 0.f};

    unsigned short* pw = &Pl[w * 16 * LDP];
    const int ntiles = min(tpc, total64 - ch * tpc);
    const int y = tid & 15, z = tid >> 4;   // V-staging coords
    const int s0base = ch * tpc * 64;

    u16x8 kr[4];
    u16x4 va4[4], vb4[4];

    auto issue = [&](int s0) {
        #pragma unroll
        for (int i = 0; i < 4; ++i) {
            const int c = tid + i * 128;
            kr[i] = *(const u16x8*)(kb16 + (base + s0 + (c >> 3)) * D_HEAD + (c & 7) * 8);
        }
        #pragma unroll
        for (int m = 0; m < 4; ++m) {
            const int sl = 2 * (z + 8 * m);
            const int d0 = y * 4;
            va4[m] = *(const u16x4*)(vb16 + (base + s0 + sl) * D_HEAD + d0);
            vb4[m] = *(const u16x4*)(vb16 + (base + s0 + sl + 1) * D_HEAD + d0);
        }
    };

    issue(s0base);

    for (int it = 0; it < ntiles; ++it) {
        const int s0 = s0base + it * 64;

        __builtin_amdgcn_s_barrier();   // prev tile's LDS reads done

        #pragma unroll
        for (int i = 0; i < 4; ++i) {
            const int c = tid + i * 128;
            *(u16x8*)(&Kl[(c >> 3) * LDK + (c & 7) * 8]) = kr[i];
        }
        #pragma unroll
        for (int m = 0; m < 4; ++m) {
            const int sl = 2 * (z + 8 * m);
            const int d0 = y * 4;
            #pragma unroll
            for (int i = 0; i < 4; ++i) {
                unsigned int pr = (unsigned int)(unsigned short)va4[m][i] |
                                  ((unsigned int)(unsigned short)vb4[m][i] << 16);
                *(unsigned int*)&Vt[(d0 + i) * LDV + sl] = pr;
            }
        }
        lds_fence_barrier();

        if (it + 1 < ntiles) issue(s0 + 64);

        // ---- QK^T: S[16 x 64] per wave ----
        f32x4 s_acc[4];
        #pragma unroll
        for (int nt = 0; nt < 4; ++nt) s_acc[nt] = (f32x4){0.f, 0.f, 0.f, 0.f};
        __builtin_amdgcn_s_setprio(1);
        #pragma unroll
        for (int nt = 0; nt < 4; ++nt)
            #pragma unroll
            for (int kk = 0; kk < 2; ++kk) {
                bf16x8 bf = ldfrag(&Kl[(nt * 16 + r) * LDK + kk * 32 + 4 * g]);
                s_acc[nt] = __builtin_amdgcn_mfma_f32_16x16x32_bf16(qf[kk], bf, s_acc[nt], 0, 0, 0);
            }
        __builtin_amdgcn_s_setprio(0);

        if (s0 + 64 > q0) {
            #pragma unroll
            for (int nt = 0; nt < 4; ++nt)
                #pragma unroll
                for (int j = 0; j < 4; ++j)
                    if (s0 + nt * 16 + r > q0 + 16 * w + 4 * g + j)
                        s_acc[nt][j] = -1e30f;
        }

        // ---- online softmax (log2 domain) ----
        float tm[4];
        #pragma unroll
        for (int j = 0; j < 4; ++j)
            tm[j] = fmaxf(fmaxf(s_acc[0][j], s_acc[1][j]),
                          fmaxf(s_acc[2][j], s_acc[3][j]));
        #pragma unroll
        for (int mask = 1; mask < 16; mask <<= 1)
            #pragma unroll
            for (int j = 0; j < 4; ++j)
                tm[j] = fmaxf(tm[j], __shfl_xor(tm[j], mask));

        float p[4][4], rs[4];
        #pragma unroll
        for (int j = 0; j < 4; ++j) {
            const float mn = fmaxf(m4[j], tm[j]);
            const float sc = exp2f(m4[j] - mn);
            m4[j] = mn;
            rs[j] = 0.f;
            #pragma unroll
            for (int nt = 0; nt < 4; ++nt) {
                p[nt][j] = exp2f(s_acc[nt][j] - mn);
                rs[j] += p[nt][j];
            }
            l4[j] *= sc;
            acc_o[0][j] *= sc; acc_o[1][j] *= sc;
            acc_o[2][j] *= sc; acc_o[3][j] *= sc;
        }
        #pragma unroll
        for (int mask = 1; mask < 16; mask <<= 1)
            #pragma unroll
            for (int j = 0; j < 4; ++j)
                rs[j] += __shfl_xor(rs[j], mask);
        #pragma unroll
        for (int j = 0; j < 4; ++j) l4[j] += rs[j];

        // ---- P -> LDS bounce (per-wave region) ----
        #pragma unroll
        for (int nt = 0; nt < 4; ++nt)
            #pragma unroll
            for (int j = 0; j < 4; ++j)
                pw[(4 * g + j) * LDP + nt * 16 + r] = f2bf(p[nt][j]);

        bf16x8 pf[2];
        #pragma unroll
        for (int kk = 0; kk < 2; ++kk)
            pf[kk] = ldfrag(&pw[r * LDP + kk * 32 + 4 * g]);

        // ---- PV: O[16 x 64] += P[16 x 64] * V[64 x 64] ----
        __builtin_amdgcn_s_setprio(1);
        #pragma unroll
        for (int dn = 0; dn < 4; ++dn)
            #pragma unroll
            for (int kk = 0; kk < 2; ++kk) {
                bf16x8 vf = ldfrag(&Vt[(dn * 16 + r) * LDV + kk * 32 + 4 * g]);
                acc_o[dn] = __builtin_amdgcn_mfma_f32_16x16x32_bf16(pf[kk], vf, acc_o[dn], 0, 0, 0);
            }
        __builtin_amdgcn_s_setprio(0);
    }

    const size_t pidx = ((size_t)(b * 64 + qt) * nch + ch);
    float* op = Op + pidx * 2048;
    #pragma unroll
    for (int j = 0; j < 4; ++j) {
        const int row = 16 * w + 4 * g + j;
        #pragma unroll
        for (int dn = 0; dn < 4; ++dn)
            op[row * 64 + dn * 16 + r] = acc_o[dn][j];
        if (r == 0) {
            Ml[pidx * 64 + row]      = m4[j];
            Ml[pidx * 64 + 32 + row] = l4[j];
        }
    }
}

// ---------------------------------------------------------------------------
// Combine partials (round-12 verbatim).
// ---------------------------------------------------------------------------
__global__ __launch_bounds__(256) void attn_combine_kernel(
    const float* __restrict__ Op, const float* __restrict__ Ml,
    float* __restrict__ out, int tpc, int nch)
{
    const int qt = blockIdx.x;
    const int b  = blockIdx.y;
    const int total64 = qt / 2 + 1;
    const int nact = (total64 + tpc - 1) / tpc;
    const size_t pbase = (size_t)(b * 64 + qt) * nch;

    __shared__ float wgt[8][32];
    __shared__ float linv[32];

    const int tid = threadIdx.x;
    if (tid < 32) {
        float M = -1e30f;
        for (int c = 0; c < nact; ++c)
            M = fmaxf(M, Ml[(pbase + c) * 64 + tid]);
        float L = 0.f;
        for (int c = 0; c < nact; ++c) {
            float wv = exp2f(Ml[(pbase + c) * 64 + tid] - M);
            wgt[c][tid] = wv;
            L += wv * Ml[(pbase + c) * 64 + 32 + tid];
        }
        linv[tid] = 1.0f / L;
    }
    __syncthreads();

    const int d  = tid & 63;
    const int r0 = tid >> 6;
    for (int row = r0; row < 32; row += 4) {
        float a = 0.f;
        for (int c = 0; c < nact; ++c)
            a += wgt[c][row] * Op[(pbase + c) * 2048 + row * 64 + d];
        out[((size_t)b * T_SEQ + qt * 32 + row) * D_HEAD + d] = a * linv[row];
    }
}

extern "C" void kernel_launch(void* const* d_in, const int* in_sizes, int n_in,
                              void* d_out, int out_size, void* d_ws, size_t ws_size,
                              hipStream_t stream) {
    const float* x  = (const float*)d_in[0];
    const float* Wq = (const float*)d_in[1];
    const float* bq = (const float*)d_in[2];
    const float* Wk = (const float*)d_in[3];
    const float* bk = (const float*)d_in[4];
    const float* Wv = (const float*)d_in[5];
    const float* bv = (const float*)d_in[6];
    float* out = (float*)d_out;

    // workspace: q,k,v bf16 (1 MB each), Wp packed (768 KB), partials at +4 MB
    __hip_bfloat16* qb = (__hip_bfloat16*)d_ws;
    __hip_bfloat16* kb = qb + (size_t)NROWS * D_HEAD;
    __hip_bfloat16* vb = kb + (size_t)NROWS * D_HEAD;
    unsigned short* Wp = (unsigned short*)(vb + (size_t)NROWS * D_HEAD);
    float* Op = (float*)((char*)d_ws + (4u << 20));

    int nch = 8;
    while (nch > 1 &&
           (4u << 20) + (size_t)256 * nch * (2048 + 64) * 4 > ws_size)
        nch >>= 1;
    const int tpc = 32 / nch;   // 64-wide s-tiles per chunk
    float* Ml = Op + (size_t)256 * nch * 2048;

    wcvt_kernel<<<192, 256, 0, stream>>>(Wq, Wk, Wv, Wp);
    proj_mfma_kernel<<<NROWS / 32, 512, 0, stream>>>(x, Wp, bq, bk, bv, qb, kb, vb);
    attn_part_kernel<<<dim3(64, nch, B_SZ), 128, 0, stream>>>(qb, kb, vb, Op, Ml, tpc, nch);
    attn_combine_kernel<<<dim3(64, B_SZ), 256, 0, stream>>>(Op, Ml, out, tpc, nch);
}